// Round 2
// baseline (1084.234 us; speedup 1.0000x reference)
//
#include <hip/hip_runtime.h>

// ---------------- problem constants ----------------
#define C_CH   512
#define HFEAT  50
#define WFEAT  50
#define NROIS  256
#define D1     25088   // C_CH * 49
#define H1     4096
#define NHEAD  105     // 21 + 84

typedef __attribute__((ext_vector_type(8))) short short8;
typedef __attribute__((ext_vector_type(4))) float f32x4;

__device__ __forceinline__ unsigned short f2bf(float f) {
  unsigned int u = __float_as_uint(f);
  return (unsigned short)((u + 0x7fffu + ((u >> 16) & 1u)) >> 16);
}

__device__ __forceinline__ short8 pack2(const float4 a, const float4 b) {
  short8 r;
  r[0] = (short)f2bf(a.x); r[1] = (short)f2bf(a.y);
  r[2] = (short)f2bf(a.z); r[3] = (short)f2bf(a.w);
  r[4] = (short)f2bf(b.x); r[5] = (short)f2bf(b.y);
  r[6] = (short)f2bf(b.z); r[7] = (short)f2bf(b.w);
  return r;
}

// ---------------- ROI max-pool (adaptive 7x7), fp32 -> bf16 ----------------
__global__ __launch_bounds__(512)
void roi_pool_kernel(const float* __restrict__ feat, const float* __restrict__ boxes,
                     unsigned short* __restrict__ pooled) {
  const int roi = blockIdx.x;
  const int bx1 = (int)(boxes[roi * 4 + 0] * 0.0625f);
  const int by1 = (int)(boxes[roi * 4 + 1] * 0.0625f);
  const int bx2 = (int)(boxes[roi * 4 + 2] * 0.0625f);
  const int by2 = (int)(boxes[roi * 4 + 3] * 0.0625f);

  const int rlo = min(max(by1, 0), HFEAT - 1);
  const int rhi = min(by2, HFEAT - 1);
  const int rn  = max(rhi - rlo + 1, 1);
  const int clo = min(max(bx1, 0), WFEAT - 1);
  const int chi = min(bx2, WFEAT - 1);
  const int cn  = max(chi - clo + 1, 1);

  for (int c = threadIdx.x; c < C_CH; c += 512) {
    const float* f = feat + (size_t)c * (HFEAT * WFEAT);
    unsigned short* op = pooled + (size_t)roi * D1 + c * 49;
    for (int i = 0; i < 7; ++i) {
      const int r0 = rlo + (i * rn) / 7;
      const int r1 = rlo + ((i + 1) * rn + 6) / 7;
      for (int j = 0; j < 7; ++j) {
        const int c0 = clo + (j * cn) / 7;
        const int c1 = clo + ((j + 1) * cn + 6) / 7;
        float m = -3.402823466e+38f;
        for (int y = r0; y < r1; ++y)
          for (int x = c0; x < c1; ++x)
            m = fmaxf(m, f[y * WFEAT + x]);
        op[i * 7 + j] = f2bf(m);
      }
    }
  }
}

// ---------------- streaming split-K MFMA GEMM: no LDS, no barriers ----------------
// A[256,K] bf16 x B[N,K] fp32 -> partials fp32 [S][256][Nt].
// Block tile: M=256 (waves split m), N=64, BK=32. Each lane holds its MFMA
// fragments in registers; B is register-prefetched one K-step ahead so HBM
// loads stay in flight across iterations (no syncthreads drain anywhere).
template <bool MASK_N>
__global__ __launch_bounds__(256)
void gemm_stream(const unsigned short* __restrict__ A,  // [256, K] bf16 bits
                 const float* __restrict__ B,           // [n_valid, K] fp32
                 float* __restrict__ part,              // [S, 256, Nt]
                 const int Nt, const int K, const int kps, const int n_valid) {
  const int bn   = blockIdx.x * 64;
  const int z    = blockIdx.z;
  const int tid  = threadIdx.x;
  const int wave = tid >> 6;
  const int lane = tid & 63;
  const int lr   = lane & 15;   // fragment row (m or n)
  const int kq   = lane >> 4;   // k-quad: k = kq*8 .. +7
  const int wm   = wave * 64;

  const size_t k0 = (size_t)z * kps;
  const unsigned short* ap = A + (size_t)(wm + lr) * K + k0 + kq * 8;
  const size_t astep = (size_t)16 * K;

  const float* bp[4];
  bool bv[4];
#pragma unroll
  for (int in = 0; in < 4; ++in) {
    const int row = bn + in * 16 + lr;
    bv[in] = !MASK_N || (row < n_valid);
    const int rowc = MASK_N ? min(row, n_valid - 1) : row;
    bp[in] = B + (size_t)rowc * K + k0 + kq * 8;
  }

  f32x4 acc[4][4];
#pragma unroll
  for (int im = 0; im < 4; ++im)
#pragma unroll
    for (int in = 0; in < 4; ++in)
      acc[im][in] = (f32x4){0.f, 0.f, 0.f, 0.f};

  const int iters = kps >> 5;
  const float4 z4 = {0.f, 0.f, 0.f, 0.f};

  // prefetch first B chunk (8 fp32 per lane per n-fragment)
  float4 bc[4][2];
#pragma unroll
  for (int in = 0; in < 4; ++in) {
    bc[in][0] = bv[in] ? *(const float4*)(bp[in])     : z4;
    bc[in][1] = bv[in] ? *(const float4*)(bp[in] + 4) : z4;
  }

  for (int it = 0; it < iters; ++it) {
    const int off = it << 5;
    // A fragments for this iter (L1/L2-hot; 16B per fragment)
    short8 af[4];
#pragma unroll
    for (int im = 0; im < 4; ++im)
      af[im] = *(const short8*)(ap + (size_t)im * astep + off);
    // prefetch next B chunk before touching current one
    float4 bnx[4][2];
    if (it + 1 < iters) {
      const int noff = off + 32;
#pragma unroll
      for (int in = 0; in < 4; ++in) {
        bnx[in][0] = bv[in] ? *(const float4*)(bp[in] + noff)     : z4;
        bnx[in][1] = bv[in] ? *(const float4*)(bp[in] + noff + 4) : z4;
      }
    }
    // convert current B to bf16 and run 16 MFMAs
    short8 bfr[4];
#pragma unroll
    for (int in = 0; in < 4; ++in) bfr[in] = pack2(bc[in][0], bc[in][1]);
#pragma unroll
    for (int im = 0; im < 4; ++im)
#pragma unroll
      for (int in = 0; in < 4; ++in)
        acc[im][in] = __builtin_amdgcn_mfma_f32_16x16x32_bf16(af[im], bfr[in], acc[im][in], 0, 0, 0);
    if (it + 1 < iters) {
#pragma unroll
      for (int in = 0; in < 4; ++in) {
        bc[in][0] = bnx[in][0];
        bc[in][1] = bnx[in][1];
      }
    }
  }

  // write fp32 partials: C/D layout col=lane&15 (n), row=kq*4+r (m)
#pragma unroll
  for (int im = 0; im < 4; ++im) {
#pragma unroll
    for (int in = 0; in < 4; ++in) {
      const int m0 = wm + im * 16 + kq * 4;
      const int n  = bn + in * 16 + lr;
      float* p = part + ((size_t)z * NROIS + m0) * Nt + n;
#pragma unroll
      for (int r = 0; r < 4; ++r)
        p[(size_t)r * Nt] = acc[im][in][r];
    }
  }
}

// ---------------- split-K reduce + bias + relu + cast to bf16 ----------------
__global__ __launch_bounds__(256)
void reduce_bias_relu(const float* __restrict__ part, const float* __restrict__ bias,
                      unsigned short* __restrict__ out, const int MN, const int nmask,
                      const int S) {
  const int idx = (blockIdx.x * 256 + threadIdx.x) * 4;
  if (idx >= MN) return;
  float4 v = *(const float4*)(part + idx);
  for (int s = 1; s < S; ++s) {
    const float4 p = *(const float4*)(part + (size_t)s * MN + idx);
    v.x += p.x; v.y += p.y; v.z += p.z; v.w += p.w;
  }
  const float4 b = *(const float4*)(bias + (idx & nmask));
  v.x = fmaxf(v.x + b.x, 0.f);
  v.y = fmaxf(v.y + b.y, 0.f);
  v.z = fmaxf(v.z + b.z, 0.f);
  v.w = fmaxf(v.w + b.w, 0.f);
  unsigned long long o = (unsigned long long)f2bf(v.x)
                       | ((unsigned long long)f2bf(v.y) << 16)
                       | ((unsigned long long)f2bf(v.z) << 32)
                       | ((unsigned long long)f2bf(v.w) << 48);
  *(unsigned long long*)(out + idx) = o;
}

// ---------------- heads: reduce + bias, split into class/regr outputs ----------------
__global__ __launch_bounds__(128)
void heads_reduce(const float* __restrict__ part, const float* __restrict__ bc,
                  const float* __restrict__ br, float* __restrict__ out, const int S) {
  const int m = blockIdx.x;
  const int n = threadIdx.x;
  if (n >= NHEAD) return;
  float v = 0.f;
  for (int s = 0; s < S; ++s) v += part[((size_t)s * NROIS + m) * 128 + n];
  if (n < 21) out[m * 21 + n] = v + bc[n];
  else        out[NROIS * 21 + m * 84 + (n - 21)] = v + br[n - 21];
}

// ---------------- launch ----------------
extern "C" void kernel_launch(void* const* d_in, const int* in_sizes, int n_in,
                              void* d_out, int out_size, void* d_ws, size_t ws_size,
                              hipStream_t stream) {
  const float* feat  = (const float*)d_in[0];
  const float* boxes = (const float*)d_in[1];
  const float* W1    = (const float*)d_in[2];
  const float* b1    = (const float*)d_in[3];
  const float* W2    = (const float*)d_in[4];
  const float* b2    = (const float*)d_in[5];
  const float* Wc    = (const float*)d_in[6];
  const float* bc    = (const float*)d_in[7];
  const float* Wr    = (const float*)d_in[8];
  const float* br    = (const float*)d_in[9];
  float* out = (float*)d_out;

  // workspace layout (bytes)
  char* ws = (char*)d_ws;
  unsigned short* pooled = (unsigned short*)(ws);                  // 256*25088*2   = 12,845,056
  float*          part   = (float*)(ws + 12845056);                // 8*256*4096*4  = 33,554,432
  unsigned short* x1     = (unsigned short*)(ws + 46399488);       // 256*4096*2    =  2,097,152
  unsigned short* x2     = (unsigned short*)(ws + 48496640);       // 256*4096*2    =  2,097,152
  float*          Wh     = (float*)(ws + 50593792);                // 105*4096*4    =  1,720,320
  float*          hpart  = (float*)(ws + 52314112);                // 16*256*128*4  =  2,097,152

  // concat Wc|Wr into one [105,4096] weight matrix
  hipMemcpyAsync(Wh, Wc, (size_t)21 * 4096 * 4, hipMemcpyDeviceToDevice, stream);
  hipMemcpyAsync(Wh + (size_t)21 * 4096, Wr, (size_t)84 * 4096 * 4, hipMemcpyDeviceToDevice, stream);

  // 1) ROI pool -> bf16 activations [256, 25088]
  roi_pool_kernel<<<NROIS, 512, 0, stream>>>(feat, boxes, pooled);

  // 2) FC1: [256,25088] x [4096,25088]^T, splitK=8 (kps=3136), Ntile=64
  gemm_stream<false><<<dim3(64, 1, 8), 256, 0, stream>>>(pooled, W1, part, H1, D1, 3136, H1);
  reduce_bias_relu<<<1024, 256, 0, stream>>>(part, b1, x1, NROIS * H1, H1 - 1, 8);

  // 3) FC2: [256,4096] x [4096,4096]^T, splitK=8 (kps=512)
  gemm_stream<false><<<dim3(64, 1, 8), 256, 0, stream>>>(x1, W2, part, H1, H1, 512, H1);
  reduce_bias_relu<<<1024, 256, 0, stream>>>(part, b2, x2, NROIS * H1, H1 - 1, 8);

  // 4) heads: [256,4096] x [105,4096]^T (N padded to 128), splitK=16 (kps=256)
  gemm_stream<true><<<dim3(2, 1, 16), 256, 0, stream>>>(x2, Wh, hpart, 128, H1, 256, NHEAD);
  heads_reduce<<<NROIS, 128, 0, stream>>>(hpart, bc, br, out, 16);
}

// Round 3
// 947.901 us; speedup vs baseline: 1.1438x; 1.1438x over previous
//
#include <hip/hip_runtime.h>

// ---------------- problem constants ----------------
#define C_CH   512
#define HFEAT  50
#define WFEAT  50
#define NROIS  256
#define D1     25088   // C_CH * 49
#define H1     4096
#define NHEAD  105     // 21 + 84

typedef __attribute__((ext_vector_type(8))) short short8;
typedef __attribute__((ext_vector_type(4))) float f32x4;

__device__ __forceinline__ unsigned short f2bf(float f) {
  unsigned int u = __float_as_uint(f);
  return (unsigned short)((u + 0x7fffu + ((u >> 16) & 1u)) >> 16);
}

__device__ __forceinline__ unsigned long long pack4(float4 v) {
  return (unsigned long long)f2bf(v.x)
       | ((unsigned long long)f2bf(v.y) << 16)
       | ((unsigned long long)f2bf(v.z) << 32)
       | ((unsigned long long)f2bf(v.w) << 48);
}

// ---------------- ROI max-pool (adaptive 7x7), fp32 -> bf16 ----------------
__global__ __launch_bounds__(512)
void roi_pool_kernel(const float* __restrict__ feat, const float* __restrict__ boxes,
                     unsigned short* __restrict__ pooled) {
  const int roi = blockIdx.x;
  const int bx1 = (int)(boxes[roi * 4 + 0] * 0.0625f);
  const int by1 = (int)(boxes[roi * 4 + 1] * 0.0625f);
  const int bx2 = (int)(boxes[roi * 4 + 2] * 0.0625f);
  const int by2 = (int)(boxes[roi * 4 + 3] * 0.0625f);

  const int rlo = min(max(by1, 0), HFEAT - 1);
  const int rhi = min(by2, HFEAT - 1);
  const int rn  = max(rhi - rlo + 1, 1);
  const int clo = min(max(bx1, 0), WFEAT - 1);
  const int chi = min(bx2, WFEAT - 1);
  const int cn  = max(chi - clo + 1, 1);

  for (int c = threadIdx.x; c < C_CH; c += 512) {
    const float* f = feat + (size_t)c * (HFEAT * WFEAT);
    unsigned short* op = pooled + (size_t)roi * D1 + c * 49;
    for (int i = 0; i < 7; ++i) {
      const int r0 = rlo + (i * rn) / 7;
      const int r1 = rlo + ((i + 1) * rn + 6) / 7;
      for (int j = 0; j < 7; ++j) {
        const int c0 = clo + (j * cn) / 7;
        const int c1 = clo + ((j + 1) * cn + 6) / 7;
        float m = -3.402823466e+38f;
        for (int y = r0; y < r1; ++y)
          for (int x = c0; x < c1; ++x)
            m = fmaxf(m, f[y * WFEAT + x]);
        op[i * 7 + j] = f2bf(m);
      }
    }
  }
}

// ---------------- LDS-staged split-K MFMA GEMM ----------------
// Tile 128(m) x 64(n) x 32(k); 256 threads = 4 waves in 2x2 (64m x 32n each).
// A[M,K] bf16 staged via global_load_lds (16B, wave-contiguous).
// B[Nv,K] fp32 loaded coalesced (8 lanes x 16B = full 128B row chunk),
// converted to bf16 in-register, written to padded LDS (stride 40 shorts).
// Deep split-K (grid.z) gives 4+ blocks/CU so other blocks' MFMA covers the
// barrier drain.
template <bool MASK_N>
__global__ __launch_bounds__(256, 4)
void gemm_tile(const unsigned short* __restrict__ A,  // [M,K] bf16 bits
               const float* __restrict__ B,           // [n_valid,K] fp32
               float* __restrict__ part,              // [S,M,Nt]
               const int M, const int Nt, const int K,
               const int kps, const int n_valid, const int nb) {
  __shared__ __align__(16) unsigned short As[128 * 32];   // 8 KB
  __shared__ __align__(16) unsigned short Bs[64 * 40];    // 5 KB (pad +8)

  const int bm = (int)(blockIdx.x / (unsigned)nb) * 128;
  const int bn = (int)(blockIdx.x % (unsigned)nb) * 64;
  const int z  = blockIdx.z;
  const int k0 = z * kps;

  const int tid  = threadIdx.x;
  const int wave = tid >> 6;
  const int lane = tid & 63;
  const int lr   = lane & 15;
  const int kq   = lane >> 4;
  const int wm   = (wave & 1) * 64;
  const int wn   = (wave >> 1) * 32;

  // A staging addresses (wave-uniform base + lane*16B, per chunk of 16 rows)
  const int arow = (lane >> 2);
  const int acol = (lane & 3) * 8;

  // B staging: 8 threads/row (16B each), 32 rows/pass, 2 passes
  const int br0 = tid >> 3;         // 0..31
  const int bc0 = (tid & 7) * 4;    // col (floats)
  int brow0 = bn + br0, brow1 = bn + 32 + br0;
  if (MASK_N) { brow0 = min(brow0, n_valid - 1); brow1 = min(brow1, n_valid - 1); }
  const float* bsrc0 = B + (size_t)brow0 * K + k0 + bc0;
  const float* bsrc1 = B + (size_t)brow1 * K + k0 + bc0;
  unsigned long long* bdst0 = (unsigned long long*)(Bs + (size_t)br0 * 40 + bc0);
  unsigned long long* bdst1 = (unsigned long long*)(Bs + (size_t)(32 + br0) * 40 + bc0);

  f32x4 acc[4][2];
#pragma unroll
  for (int im = 0; im < 4; ++im)
#pragma unroll
    for (int in = 0; in < 2; ++in)
      acc[im][in] = (f32x4){0.f, 0.f, 0.f, 0.f};

  const int iters = kps >> 5;
  for (int it = 0; it < iters; ++it) {
    const int kk = it << 5;
    __syncthreads();
    // ---- stage A (128x32 bf16, 8KB): 2 global_load_lds per wave ----
#pragma unroll
    for (int i = 0; i < 2; ++i) {
      const int chunk = wave * 2 + i;  // wave-uniform
      const unsigned short* g =
          A + (size_t)(bm + chunk * 16 + arow) * K + k0 + kk + acol;
      __builtin_amdgcn_global_load_lds(
          (const __attribute__((address_space(1))) void*)g,
          (__attribute__((address_space(3))) void*)(As + chunk * 512),
          16, 0, 0);
    }
    // ---- stage B (64x32 fp32 -> bf16): coalesced 128B row chunks ----
    const float4 v0 = *(const float4*)(bsrc0 + kk);
    const float4 v1 = *(const float4*)(bsrc1 + kk);
    *bdst0 = pack4(v0);
    *bdst1 = pack4(v1);
    __syncthreads();
    // ---- fragments + 8 MFMAs per wave ----
    short8 af[4], bfr[2];
#pragma unroll
    for (int im = 0; im < 4; ++im)
      af[im] = *(const short8*)(As + (wm + im * 16 + lr) * 32 + kq * 8);
#pragma unroll
    for (int in = 0; in < 2; ++in)
      bfr[in] = *(const short8*)(Bs + (wn + in * 16 + lr) * 40 + kq * 8);
#pragma unroll
    for (int im = 0; im < 4; ++im)
#pragma unroll
      for (int in = 0; in < 2; ++in)
        acc[im][in] = __builtin_amdgcn_mfma_f32_16x16x32_bf16(af[im], bfr[in], acc[im][in], 0, 0, 0);
  }

  // ---- write fp32 partials: C/D layout col=lane&15 (n), row=kq*4+r (m) ----
#pragma unroll
  for (int im = 0; im < 4; ++im) {
#pragma unroll
    for (int in = 0; in < 2; ++in) {
      const int m0 = bm + wm + im * 16 + kq * 4;
      const int n  = bn + wn + in * 16 + lr;
      float* p = part + ((size_t)z * M + m0) * Nt + n;
#pragma unroll
      for (int r = 0; r < 4; ++r)
        p[(size_t)r * Nt] = acc[im][in][r];
    }
  }
}

// ---------------- split-K reduce + bias + relu + cast to bf16 ----------------
__global__ __launch_bounds__(256)
void reduce_bias_relu(const float* __restrict__ part, const float* __restrict__ bias,
                      unsigned short* __restrict__ out, const int MN, const int nmask,
                      const int S) {
  const int idx = (blockIdx.x * 256 + threadIdx.x) * 4;
  if (idx >= MN) return;
  float4 v = *(const float4*)(part + idx);
  for (int s = 1; s < S; ++s) {
    const float4 p = *(const float4*)(part + (size_t)s * MN + idx);
    v.x += p.x; v.y += p.y; v.z += p.z; v.w += p.w;
  }
  const float4 b = *(const float4*)(bias + (idx & nmask));
  v.x = fmaxf(v.x + b.x, 0.f);
  v.y = fmaxf(v.y + b.y, 0.f);
  v.z = fmaxf(v.z + b.z, 0.f);
  v.w = fmaxf(v.w + b.w, 0.f);
  unsigned long long o = (unsigned long long)f2bf(v.x)
                       | ((unsigned long long)f2bf(v.y) << 16)
                       | ((unsigned long long)f2bf(v.z) << 32)
                       | ((unsigned long long)f2bf(v.w) << 48);
  *(unsigned long long*)(out + idx) = o;
}

// ---------------- heads: reduce + bias, split into class/regr outputs ----------------
__global__ __launch_bounds__(128)
void heads_reduce(const float* __restrict__ part, const float* __restrict__ bc,
                  const float* __restrict__ br, float* __restrict__ out, const int S) {
  const int m = blockIdx.x;
  const int n = threadIdx.x;
  if (n >= NHEAD) return;
  float v = 0.f;
  for (int s = 0; s < S; ++s) v += part[((size_t)s * NROIS + m) * 128 + n];
  if (n < 21) out[m * 21 + n] = v + bc[n];
  else        out[NROIS * 21 + m * 84 + (n - 21)] = v + br[n - 21];
}

// ---------------- launch ----------------
extern "C" void kernel_launch(void* const* d_in, const int* in_sizes, int n_in,
                              void* d_out, int out_size, void* d_ws, size_t ws_size,
                              hipStream_t stream) {
  const float* feat  = (const float*)d_in[0];
  const float* boxes = (const float*)d_in[1];
  const float* W1    = (const float*)d_in[2];
  const float* b1    = (const float*)d_in[3];
  const float* W2    = (const float*)d_in[4];
  const float* b2    = (const float*)d_in[5];
  const float* Wc    = (const float*)d_in[6];
  const float* bc    = (const float*)d_in[7];
  const float* Wr    = (const float*)d_in[8];
  const float* br    = (const float*)d_in[9];
  float* out = (float*)d_out;

  // workspace layout (bytes)
  char* ws = (char*)d_ws;
  unsigned short* pooled = (unsigned short*)(ws);               // 12,845,056
  float*          part   = (float*)(ws + 12845056);             // 16*256*4096*4 = 67,108,864
  unsigned short* x1     = (unsigned short*)(ws + 79953920);    // 2,097,152
  unsigned short* x2     = (unsigned short*)(ws + 82051072);    // 2,097,152
  float*          Wh     = (float*)(ws + 84148224);             // 1,720,320
  float*          hpart  = (float*)(ws + 85868544);             // 16*256*128*4 = 2,097,152

  // concat Wc|Wr into one [105,4096] weight matrix
  hipMemcpyAsync(Wh, Wc, (size_t)21 * 4096 * 4, hipMemcpyDeviceToDevice, stream);
  hipMemcpyAsync(Wh + (size_t)21 * 4096, Wr, (size_t)84 * 4096 * 4, hipMemcpyDeviceToDevice, stream);

  // 1) ROI pool -> bf16 activations [256, 25088]
  roi_pool_kernel<<<NROIS, 512, 0, stream>>>(feat, boxes, pooled);

  // 2) FC1: [256,25088] x [4096,25088]^T, tile 128x64, splitK=16 (kps=1568)
  gemm_tile<false><<<dim3(128, 1, 16), 256, 0, stream>>>(pooled, W1, part,
      NROIS, H1, D1, 1568, H1, 64);
  reduce_bias_relu<<<1024, 256, 0, stream>>>(part, b1, x1, NROIS * H1, H1 - 1, 16);

  // 3) FC2: [256,4096] x [4096,4096]^T, splitK=8 (kps=512)
  gemm_tile<false><<<dim3(128, 1, 8), 256, 0, stream>>>(x1, W2, part,
      NROIS, H1, H1, 512, H1, 64);
  reduce_bias_relu<<<1024, 256, 0, stream>>>(part, b2, x2, NROIS * H1, H1 - 1, 8);

  // 4) heads: [256,4096] x [105,4096]^T (N padded to 128), splitK=16 (kps=256)
  gemm_tile<true><<<dim3(4, 1, 16), 256, 0, stream>>>(x2, Wh, hpart,
      NROIS, 128, H1, 256, NHEAD, 2);
  heads_reduce<<<NROIS, 128, 0, stream>>>(hpart, bc, br, out, 16);
}